// Round 16
// baseline (526.915 us; speedup 1.0000x reference)
//
#include <hip/hip_runtime.h>
#include <hip/hip_bf16.h>

#define B_ 16
#define C_ 768
#define S_ 1024
#define H_ 12
#define D_ 64
#define I_ 3072
#define T_ (B_ * S_)   // 16384 tokens
#define LOG2E 1.4426950408889634f

typedef unsigned short u16;
typedef unsigned long long u64;
typedef __attribute__((ext_vector_type(8))) short bf16x8;
typedef __attribute__((ext_vector_type(4))) float f32x4;
typedef __attribute__((ext_vector_type(16))) float f32x16;
typedef __attribute__((ext_vector_type(4))) unsigned short us4;

__device__ __forceinline__ u16 bf16b(float f) {
    __hip_bfloat16 h = __float2bfloat16(f);
    return *reinterpret_cast<u16*>(&h);
}
__device__ __forceinline__ float b2f(u16 r) {
    __hip_bfloat16 h = *reinterpret_cast<__hip_bfloat16*>(&r);
    return __bfloat162float(h);
}
// raw v_exp_f32 (2^x), no libm denormal fixup — inputs here are |x| << 126
__device__ __forceinline__ float exp2_raw(float x) {
    return __builtin_amdgcn_exp2f(x);
}

__device__ __forceinline__ void gload16(const void* g, void* l) {
    __builtin_amdgcn_global_load_lds(
        (const __attribute__((address_space(1))) unsigned int*)g,
        (__attribute__((address_space(3))) unsigned int*)l, 16, 0, 0);
}

// ---------------------------------------------------------------------------
// Weight f32 -> bf16: 4 [C,C] mats into contiguous dest
// ---------------------------------------------------------------------------
__global__ __launch_bounds__(256) void cvt_w4(
    const float* __restrict__ w0, const float* __restrict__ w1,
    const float* __restrict__ w2, const float* __restrict__ w3,
    u16* __restrict__ o, int n4) {
    const int sel = blockIdx.y;
    const float* w = sel == 0 ? w0 : sel == 1 ? w1 : sel == 2 ? w2 : w3;
    u16* op = o + (size_t)sel * n4 * 4;
    int i = blockIdx.x * 256 + threadIdx.x;
    if (i < n4) {
        float4 v = ((const float4*)w)[i];
        us4 r = { bf16b(v.x), bf16b(v.y), bf16b(v.z), bf16b(v.w) };
        ((us4*)op)[i] = r;
    }
}
__global__ __launch_bounds__(256) void cvt_w2(
    const float* __restrict__ w0, const float* __restrict__ w1,
    u16* __restrict__ o, int n4) {
    const int sel = blockIdx.y;
    const float* w = sel == 0 ? w0 : w1;
    u16* op = o + (size_t)sel * n4 * 4;
    int i = blockIdx.x * 256 + threadIdx.x;
    if (i < n4) {
        float4 v = ((const float4*)w)[i];
        us4 r = { bf16b(v.x), bf16b(v.y), bf16b(v.z), bf16b(v.w) };
        ((us4*)op)[i] = r;
    }
}

// ---------------------------------------------------------------------------
// x [B,C,S] f32 -> xt16 [B,S,C] bf16
// ---------------------------------------------------------------------------
__global__ __launch_bounds__(256) void trans_in(const float* __restrict__ in,
                                                u16* __restrict__ o16) {
    const int b = blockIdx.z, c0 = blockIdx.y * 64, s0 = blockIdx.x * 64;
    __shared__ float t[64][65];
    const int cl = threadIdx.x & 63, rw = threadIdx.x >> 6;
    #pragma unroll
    for (int p = 0; p < 16; ++p) {
        int cr = rw + p * 4;
        t[cr][cl] = in[((size_t)b * C_ + c0 + cr) * S_ + s0 + cl];
    }
    __syncthreads();
    #pragma unroll
    for (int p = 0; p < 16; ++p) {
        int sr = rw + p * 4;
        o16[((size_t)b * S_ + s0 + sr) * C_ + c0 + cl] = bf16b(t[cl][sr]);
    }
}

// ---------------------------------------------------------------------------
// f32 [B,S,C] -> f32 [B,C,S] with fused LayerNorm apply (stats precomputed)
// ---------------------------------------------------------------------------
__global__ __launch_bounds__(256) void trans_out_ln(
    const float* __restrict__ in, const float2* __restrict__ st,
    const float* __restrict__ g, const float* __restrict__ be,
    float* __restrict__ out) {
    const int b = blockIdx.z, c0 = blockIdx.y * 64, s0 = blockIdx.x * 64;
    __shared__ float t[64][65];
    const int cl = threadIdx.x & 63, rw = threadIdx.x >> 6;
    const float gc = g[c0 + cl], bc = be[c0 + cl];
    #pragma unroll
    for (int p = 0; p < 16; ++p) {
        int sr = rw + p * 4;
        float2 ms = st[(size_t)b * S_ + s0 + sr];
        float v = in[((size_t)b * S_ + s0 + sr) * C_ + c0 + cl];
        t[sr][cl] = (v - ms.x) * ms.y * gc + bc;
    }
    __syncthreads();
    #pragma unroll
    for (int p = 0; p < 16; ++p) {
        int cr = rw + p * 4;
        out[((size_t)b * C_ + c0 + cr) * S_ + s0 + cl] = t[cl][cr];
    }
}

// ---------------------------------------------------------------------------
// bf16 MFMA GEMM, 32x32x16 frags: out[t, o] = sum_k A[t,k] * W[o,k]
// 128(M) x BN tile, BK=32 DOUBLE-BUFFERED single-barrier loop (attn-proven):
// stage k-tile t+1 into buf^1 BEFORE computing tile t; one barrier/iter both
// guards buffer reuse and drains the prefetch. LDS unchanged vs BK=64 single
// buffer (BN=128: 32KB, BN=64: 24KB) -> occupancy preserved (R13 lesson).
// 64B rows: chunk swizzle S'(row) = (row>>1)&3 -> 2 lanes/slot per 16-lane
// phase (measured-free multiplicity). XCD-aware bijective block swizzle.
// MODE 3: out_bf16 = gelu_tanh(acc + bias)   (rcp + raw exp2)
// MODE 5: QKV fused: Q region scaled 0.125*log2e; V region (n0>=1536) is
//         written TRANSPOSED to vt16 [B,C,S] via LDS (res = vt16 ptr).
// MODE 6: out_f32  = acc + bias + bf16(res)
// ---------------------------------------------------------------------------
template <int MODE, int BN>
__global__ __launch_bounds__(256) void gemm_bt(
    const u16* __restrict__ A, int ldA,
    const u16* __restrict__ W, int ldW,
    const float* __restrict__ bias,
    const float* __restrict__ bias2,
    const float* __restrict__ bias3,
    const void* __restrict__ res,
    void* __restrict__ outp, int ldO,
    int K, int nn)
{
    constexpr int NI = BN / 64;     // 32-wide n-frags per wave (128->2, 64->1)
    const int tid = threadIdx.x;
    const int wave = tid >> 6, lane = tid & 63;
    const int wr = wave >> 1, wc = wave & 1;

    // XCD-aware bijective swizzle: XCD x gets a contiguous m-chunk, n fastest
    const int qx = gridDim.x >> 3;
    const int swz = (blockIdx.x & 7) * qx + (blockIdx.x >> 3);
    const int m0 = (swz / nn) * 128, n0 = (swz % nn) * BN;

    // dbuf: Al[2] = 2*128*32 u16, Bl[2] = 2*BN*32 u16
    __shared__ __align__(16) u16 SB[2 * 128 * 32 + 2 * BN * 32];
    u16* AlB = SB;                     // + bf*4096
    u16* BlB = SB + 2 * 128 * 32;      // + bf*BN*32

    f32x16 acc[2][NI] = {};

    const int srow = tid >> 2;                        // staging row (0..63)
    // inverse-swizzled source chunk: S'(r) = (r>>1)&3
    const int swzc = ((tid & 3) ^ ((srow >> 1) & 3)) * 8;

    auto stage = [&](int k0, int bf) {
        u16* Ad = AlB + bf * 4096;
        u16* Bd = BlB + bf * BN * 32;
        #pragma unroll
        for (int p = 0; p < 2; ++p)
            gload16(A + (size_t)(m0 + p * 64 + srow) * ldA + k0 + swzc,
                    Ad + p * 2048 + wave * 512);
        #pragma unroll
        for (int p = 0; p < BN / 64; ++p)
            gload16(W + (size_t)(n0 + p * 64 + srow) * ldW + k0 + swzc,
                    Bd + p * 2048 + wave * 512);
    };

    stage(0, 0);
    __syncthreads();                   // buf 0 ready

    const int nk = K >> 5;
    for (int kt = 0; kt < nk; ++kt) {
        if (kt + 1 < nk) stage((kt + 1) << 5, (kt + 1) & 1);   // prefetch
        const u16* Ac = AlB + (kt & 1) * 4096;
        const u16* Bc = BlB + (kt & 1) * BN * 32;

        #pragma unroll
        for (int kc = 0; kc < 2; ++kc) {
            bf16x8 aF[2], bF[NI];
            #pragma unroll
            for (int mi = 0; mi < 2; ++mi) {
                int row = wr * 64 + mi * 32 + (lane & 31);
                int ch = (2 * kc + (lane >> 5)) ^ ((row >> 1) & 3);
                aF[mi] = *(const bf16x8*)(Ac + row * 32 + ch * 8);
            }
            #pragma unroll
            for (int ni = 0; ni < NI; ++ni) {
                int row = wc * (BN / 2) + ni * 32 + (lane & 31);
                int ch = (2 * kc + (lane >> 5)) ^ ((row >> 1) & 3);
                bF[ni] = *(const bf16x8*)(Bc + row * 32 + ch * 8);
            }
            #pragma unroll
            for (int mi = 0; mi < 2; ++mi)
                #pragma unroll
                for (int ni = 0; ni < NI; ++ni)
                    acc[mi][ni] = __builtin_amdgcn_mfma_f32_32x32x16_bf16(
                        aF[mi], bF[ni], acc[mi][ni], 0, 0, 0);
        }
        __syncthreads();   // guards buf reuse (stage kt+2 -> buf[kt&1]) and
                           // drains prefetch so buf[(kt+1)&1] is ready
    }

    // ---- V-block path (MODE 5, n0 >= 1536): bias + LDS transpose -> vt16
    if constexpr (MODE == 5 && BN == 128) {
        if (n0 >= 2 * C_) {
            u16* tile = SB;   // 32KB = 128 cols x 128 rows u16
            __syncthreads();  // all waves done reading staging LDS
            #pragma unroll
            for (int ni = 0; ni < NI; ++ni) {
                const int col = wc * 64 + ni * 32 + (lane & 31);
                const float bo = bias3[n0 - 2 * C_ + col];
                #pragma unroll
                for (int mi = 0; mi < 2; ++mi) {
                    const int rbase = wr * 64 + mi * 32 + 4 * (lane >> 5);
                    #pragma unroll
                    for (int g = 0; g < 4; ++g) {
                        u64 pk = (u64)bf16b(acc[mi][ni][4 * g + 0] + bo)
                               | ((u64)bf16b(acc[mi][ni][4 * g + 1] + bo) << 16)
                               | ((u64)bf16b(acc[mi][ni][4 * g + 2] + bo) << 32)
                               | ((u64)bf16b(acc[mi][ni][4 * g + 3] + bo) << 48);
                        int a = col * 128 + ((rbase + 8 * g) ^ ((col & 31) << 2));
                        *(u64*)(tile + a) = pk;
                    }
                }
            }
            __syncthreads();
            u16* vout = (u16*)res;                 // vt16 [B,C,S]
            const int bb = m0 >> 10, s0 = m0 & 1023;
            #pragma unroll 4
            for (int i = 0; i < 32; ++i) {
                const int c = wave * 32 + i;
                const int a = c * 128 + ((2 * lane) ^ ((c & 31) << 2));
                unsigned w = *(const unsigned*)(tile + a);
                *(unsigned*)(vout + ((size_t)(bb * C_ + (n0 - 2 * C_) + c)) * S_
                             + s0 + 2 * lane) = w;
            }
            return;
        }
    }

    // epilogue; C/D layout: col=lane&31, row=(reg&3)+8*(reg>>2)+4*(lane>>5)
    #pragma unroll
    for (int ni = 0; ni < NI; ++ni) {
        const int o = n0 + wc * (BN / 2) + ni * 32 + (lane & 31);
        float bo, sc = 1.0f;
        if constexpr (MODE == 5) {
            if (o < C_)          { bo = bias[o];            sc = 0.125f * LOG2E; }
            else                 { bo = bias2[o - C_]; }
        } else {
            bo = bias[o];
        }
        #pragma unroll
        for (int mi = 0; mi < 2; ++mi) {
            const int rbase = m0 + wr * 64 + mi * 32 + 4 * (lane >> 5);
            #pragma unroll
            for (int reg = 0; reg < 16; ++reg) {
                const int row = rbase + (reg & 3) + 8 * (reg >> 2);
                const size_t idx = (size_t)row * ldO + o;
                float v = acc[mi][ni][reg];
                if constexpr (MODE == 3) {
                    float u = v + bo;
                    float z2 = (1.5957691216057308f * LOG2E) * (u + 0.044715f * u * u * u);
                    float e = exp2_raw(z2);
                    float r = __builtin_amdgcn_rcpf(e + 1.0f);
                    ((u16*)outp)[idx] = bf16b(u - u * r);
                } else if constexpr (MODE == 5) {
                    ((u16*)outp)[idx] = bf16b((v + bo) * sc);
                } else {  // MODE 6
                    ((float*)outp)[idx] = v + bo + b2f(((const u16*)res)[idx]);
                }
            }
        }
    }
}

// ---------------------------------------------------------------------------
// Flash attention: R6 structure + XCD-grouping swizzle + raw-exp2 softmax +
// T5 s_setprio around MFMA clusters (m191). No-max softmax, deferred
// l-reduction, 40KB LDS rotation: R0=Q then odd-V, R1=even-K, R2=even-V,
// R3=odd-K. global_load_lds prefetch of next K/V tile during compute;
// 1 barrier/iter. Unswapped QK^T; scalar b16 P-stores (0-conflict).
// ---------------------------------------------------------------------------
#define LDQK 2304
__global__ __launch_bounds__(256) void attn(
    const u16* __restrict__ Q, const u16* __restrict__ Kt,
    const u16* __restrict__ VT, const float* __restrict__ mask,
    u16* __restrict__ ctx)
{
    const int tid = threadIdx.x, wave = tid >> 6, lane = tid & 63;

    // XCD-grouping swizzle (bijective): all 16 q-tiles of one (b,h) share
    // l%8 => one XCD under round-robin dispatch.
    const int l = blockIdx.x + 16 * blockIdx.y;   // 0..3071
    const int xc = l & 7, m = l >> 3;             // m: 0..383
    const int bh = xc * 24 + (m >> 4);            // 24 (b,h) pairs per XCD
    const int sq0 = (m & 15) * 64;
    const int b = bh / H_, h = bh - b * H_;

    __shared__ __align__(16) u16 R[4][64 * 64];   // 32KB rotating
    __shared__ __align__(16) u16 Ps[4][16 * 64];  // 8KB

    const int strow0 = tid >> 3;          // staging row, pass 0 (0..31)
    const int strow1 = 32 + (tid >> 3);   // pass 1
    const int stc = tid & 7;              // chunk in row

    auto stageK = [&](int t, u16* dst) {
        const int sk0 = t * 64;
        gload16(Kt + (size_t)(b * S_ + sk0 + strow0) * LDQK + h * 64 + ((stc ^ (strow0 & 7)) * 8),
                dst + wave * 512);
        gload16(Kt + (size_t)(b * S_ + sk0 + strow1) * LDQK + h * 64 + ((stc ^ (strow1 & 7)) * 8),
                dst + 2048 + wave * 512);
    };
    auto stageV = [&](int t, u16* dst) {
        const int sk0 = t * 64;
        gload16(VT + (size_t)(b * C_ + h * 64 + strow0) * S_ + sk0 + ((stc ^ (strow0 & 7)) * 8),
                dst + wave * 512);
        gload16(VT + (size_t)(b * C_ + h * 64 + strow1) * S_ + sk0 + ((stc ^ (strow1 & 7)) * 8),
                dst + 2048 + wave * 512);
    };

    // stage Q into R0, first K/V into R1/R2
    gload16(Q + (size_t)(b * S_ + sq0 + strow0) * LDQK + h * 64 + ((stc ^ (strow0 & 7)) * 8),
            R[0] + wave * 512);
    gload16(Q + (size_t)(b * S_ + sq0 + strow1) * LDQK + h * 64 + ((stc ^ (strow1 & 7)) * 8),
            R[0] + 2048 + wave * 512);
    stageK(0, R[1]);
    stageV(0, R[2]);
    __syncthreads();

    // Q fragments (loop-invariant)
    bf16x8 aQ[2];
    #pragma unroll
    for (int ks = 0; ks < 2; ++ks) {
        int row = wave * 16 + (lane & 15);
        int c16 = ks * 4 + (lane >> 4);
        aQ[ks] = *(const bf16x8*)(R[0] + row * 64 + ((c16 ^ (row & 7)) * 8));
    }
    __syncthreads();   // all aQ reads done before R0 is reused for V1

    f32x4 oacc[4] = {};
    float l_part[4] = {0.f, 0.f, 0.f, 0.f};
    const float* mbase = mask + (size_t)b * S_;

    for (int t = 0; t < 16; ++t) {
        const int sk0 = t * 64;
        const u16* Kc = R[1 + 2 * (t & 1)];       // R1 / R3
        const u16* Vc = R[2 - 2 * (t & 1)];       // R2 / R0
        if (t < 15) {
            stageK(t + 1, R[1 + 2 * ((t + 1) & 1)]);
            stageV(t + 1, R[2 - 2 * ((t + 1) & 1)]);
        }

        // ---- QK^T (Q pre-scaled by 0.125*log2e)
        f32x4 sacc[4] = {};
        __builtin_amdgcn_s_setprio(1);
        #pragma unroll
        for (int ni = 0; ni < 4; ++ni) {
            #pragma unroll
            for (int ks = 0; ks < 2; ++ks) {
                int row = ni * 16 + (lane & 15);
                int c16 = ks * 4 + (lane >> 4);
                bf16x8 bK = *(const bf16x8*)(Kc + row * 64 + ((c16 ^ (row & 7)) * 8));
                sacc[ni] = __builtin_amdgcn_mfma_f32_16x16x32_bf16(aQ[ks], bK, sacc[ni], 0, 0, 0);
            }
        }
        __builtin_amdgcn_s_setprio(0);

        float mk[4];
        #pragma unroll
        for (int ni = 0; ni < 4; ++ni)
            mk[ni] = mbase[sk0 + ni * 16 + (lane & 15)] * LOG2E;

        // ---- no-max softmax numerator: p = 2^(s + mask*log2e), raw v_exp
        #pragma unroll
        for (int r = 0; r < 4; ++r) {
            const int prow = (lane >> 4) * 4 + r;
            #pragma unroll
            for (int ni = 0; ni < 4; ++ni) {
                float p = exp2_raw(sacc[ni][r] + mk[ni]);
                l_part[r] += p;
                int pcol = ni * 16 + (lane & 15);
                int cc = (pcol >> 3) ^ (prow & 7);
                Ps[wave][prow * 64 + cc * 8 + (pcol & 7)] = bf16b(p);
            }
        }

        // ---- PV accumulate (no rescale needed)
        __builtin_amdgcn_s_setprio(1);
        #pragma unroll
        for (int ks = 0; ks < 2; ++ks) {
            int prow = lane & 15;
            int pc16 = ks * 4 + (lane >> 4);
            bf16x8 aP = *(const bf16x8*)(&Ps[wave][prow * 64 + ((pc16 ^ (prow & 7)) * 8)]);
            #pragma unroll
            for (int ni = 0; ni < 4; ++ni) {
                int vrow = ni * 16 + (lane & 15);
                int vc16 = ks * 4 + (lane >> 4);
                bf16x8 bV = *(const bf16x8*)(Vc + vrow * 64 + ((vc16 ^ (vrow & 7)) * 8));
                oacc[ni] = __builtin_amdgcn_mfma_f32_16x16x32_bf16(aP, bV, oacc[ni], 0, 0, 0);
            }
        }
        __builtin_amdgcn_s_setprio(0);
        __syncthreads();   // drains prefetch; guards K/V/Ps region reuse
    }

    // ---- final l reduction (once) + epilogue
    float inv[4];
    #pragma unroll
    for (int r = 0; r < 4; ++r) {
        float lt = l_part[r];
        #pragma unroll
        for (int off = 8; off >= 1; off >>= 1) lt += __shfl_xor(lt, off);
        inv[r] = 1.0f / lt;
    }
    #pragma unroll
    for (int ni = 0; ni < 4; ++ni) {
        #pragma unroll
        for (int r = 0; r < 4; ++r) {
            int rowD = (lane >> 4) * 4 + r;
            int token = b * S_ + sq0 + wave * 16 + rowD;
            int d = ni * 16 + (lane & 15);
            ctx[(size_t)token * C_ + h * 64 + d] = bf16b(oacc[ni][r] * inv[r]);
        }
    }
}

// ---------------------------------------------------------------------------
// Row LayerNorm (token-major). Block = 4 waves = 4 tokens. Full apply -> bf16.
// ---------------------------------------------------------------------------
__global__ __launch_bounds__(256) void ln_rows(
    const float* __restrict__ Y, const float* __restrict__ g,
    const float* __restrict__ be, u16* __restrict__ out16)
{
    const int wave = threadIdx.x >> 6, lane = threadIdx.x & 63;
    const size_t t = blockIdx.x * 4 + wave;
    const float4* y4 = (const float4*)(Y + t * C_);
    float4 v[3];
    float sum = 0.f, ss = 0.f;
    #pragma unroll
    for (int j = 0; j < 3; ++j) {
        v[j] = y4[lane + j * 64];
        sum += v[j].x + v[j].y + v[j].z + v[j].w;
        ss  += v[j].x * v[j].x + v[j].y * v[j].y + v[j].z * v[j].z + v[j].w * v[j].w;
    }
    #pragma unroll
    for (int off = 32; off >= 1; off >>= 1) {
        sum += __shfl_xor(sum, off);
        ss  += __shfl_xor(ss, off);
    }
    const float mu = sum * (1.0f / C_);
    const float var = ss * (1.0f / C_) - mu * mu;
    const float rs = rsqrtf(var + 1e-12f);
    #pragma unroll
    for (int j = 0; j < 3; ++j) {
        int c4 = lane + j * 64;
        float4 gv = ((const float4*)g)[c4];
        float4 bv = ((const float4*)be)[c4];
        us4 pk = { bf16b((v[j].x - mu) * rs * gv.x + bv.x),
                   bf16b((v[j].y - mu) * rs * gv.y + bv.y),
                   bf16b((v[j].z - mu) * rs * gv.z + bv.z),
                   bf16b((v[j].w - mu) * rs * gv.w + bv.w) };
        ((us4*)(out16 + t * C_))[c4] = pk;
    }
}

// ---------------------------------------------------------------------------
// LayerNorm stats only: mu, rstd per token -> float2
// ---------------------------------------------------------------------------
__global__ __launch_bounds__(256) void ln_stats(
    const float* __restrict__ Y, float2* __restrict__ st)
{
    const int wave = threadIdx.x >> 6, lane = threadIdx.x & 63;
    const size_t t = blockIdx.x * 4 + wave;
    const float4* y4 = (const float4*)(Y + t * C_);
    float sum = 0.f, ss = 0.f;
    #pragma unroll
    for (int j = 0; j < 3; ++j) {
        float4 v = y4[lane + j * 64];
        sum += v.x + v.y + v.z + v.w;
        ss  += v.x * v.x + v.y * v.y + v.z * v.z + v.w * v.w;
    }
    #pragma unroll
    for (int off = 32; off >= 1; off >>= 1) {
        sum += __shfl_xor(sum, off);
        ss  += __shfl_xor(ss, off);
    }
    if (lane == 0) {
        const float mu = sum * (1.0f / C_);
        const float var = ss * (1.0f / C_) - mu * mu;
        st[t] = make_float2(mu, rsqrtf(var + 1e-12f));
    }
}

// ---------------------------------------------------------------------------
extern "C" void kernel_launch(void* const* d_in, const int* in_sizes, int n_in,
                              void* d_out, int out_size, void* d_ws, size_t ws_size,
                              hipStream_t stream)
{
    const float* x     = (const float*)d_in[0];
    const float* mask  = (const float*)d_in[1];
    const float* Wq    = (const float*)d_in[2];
    const float* bq    = (const float*)d_in[3];
    const float* Wk    = (const float*)d_in[4];
    const float* bk    = (const float*)d_in[5];
    const float* Wv    = (const float*)d_in[6];
    const float* bv    = (const float*)d_in[7];
    const float* Wpost = (const float*)d_in[8];
    const float* bpost = (const float*)d_in[9];
    const float* gpost = (const float*)d_in[10];
    const float* betap = (const float*)d_in[11];
    const float* Wint  = (const float*)d_in[12];
    const float* bint  = (const float*)d_in[13];
    const float* Wout  = (const float*)d_in[14];
    const float* bout  = (const float*)d_in[15];
    const float* gout  = (const float*)d_in[16];
    const float* betao = (const float*)d_in[17];

    char* ws = (char*)d_ws;
    const size_t OFF0 = 0;                       // ctx16 (25MB) -> ffnout f32 (50MB)
    const size_t OFF1 = 50331648;                // xt16 (25.2MB) -> post16
    const size_t OFF2 = 75497472;                // qkv16 [T,2304] -> postpre -> inter
    const size_t OFF3 = 150994944;               // vt16 (25.2MB) / tail of inter
    const size_t OFFW = 176160768;               // weights (13.5MB)
    const size_t OFFS = 190316544;               // LN2 stats (128KB)

    u16*   ctx16   = (u16*)(ws + OFF0);
    float* ffnout  = (float*)(ws + OFF0);
    u16*   xt16    = (u16*)(ws + OFF1);
    u16*   post16  = (u16*)(ws + OFF1);
    u16*   qkv16   = (u16*)(ws + OFF2);
    float* postpre = (float*)(ws + OFF2);
    u16*   inter   = (u16*)(ws + OFF2);          // [T,3072] bf16 (OFF2+OFF3)
    u16*   vt16    = (u16*)(ws + OFF3);
    float2* st2    = (float2*)(ws + OFFS);

    u16* wq16 = (u16*)(ws + OFFW);               // wq,wk,wv,wp contiguous
    u16* wp16 = wq16 + 3 * (size_t)C_ * C_;
    u16* wi16 = wq16 + 4 * (size_t)C_ * C_;      // wi,wo contiguous
    u16* wo16 = wi16 + (size_t)I_ * C_;

    dim3 blk(256);
    const int n4w = C_ * C_ / 4, n4i = I_ * C_ / 4;
    cvt_w4<<<dim3((n4w + 255) / 256, 4), blk, 0, stream>>>(Wq, Wk, Wv, Wpost, wq16, n4w);
    cvt_w2<<<dim3((n4i + 255) / 256, 2), blk, 0, stream>>>(Wint, Wout, wi16, n4i);

    trans_in<<<dim3(16, 12, 16), blk, 0, stream>>>(x, xt16);

    // fused QKV projection -> Q,K into [T,2304]; V transposed to vt16 [B,C,S]
    gemm_bt<5, 128><<<dim3(128 * 18), blk, 0, stream>>>(xt16, C_, wq16, C_, bq, bk, bv,
                                                        vt16, qkv16, 3 * C_, C_, 18);

    attn<<<dim3(16, B_ * H_), blk, 0, stream>>>(qkv16, qkv16 + C_, vt16, mask, ctx16);

    // post projection + bf16 residual(x) -> f32, then LN1 -> bf16
    gemm_bt<6, 64><<<dim3(128 * 12), blk, 0, stream>>>(ctx16, C_, wp16, C_, bpost, nullptr, nullptr,
                                                       xt16, postpre, C_, C_, 12);
    ln_rows<<<dim3(T_ / 4), blk, 0, stream>>>(postpre, gpost, betap, post16);

    // FFN up (full N=3072) + GELU(tanh,rcp,raw exp2) -> bf16 inter
    gemm_bt<3, 128><<<dim3(128 * 24), blk, 0, stream>>>(post16, C_, wi16, C_, bint, nullptr, nullptr,
                                                        nullptr, inter, I_, C_, 24);
    // FFN down (K=3072) + bf16 residual(post16) -> f32
    gemm_bt<6, 64><<<dim3(128 * 12), blk, 0, stream>>>(inter, I_, wo16, I_, bout, nullptr, nullptr,
                                                       post16, ffnout, C_, I_, 12);

    // LN2: stats pass + apply fused into the output transpose
    ln_stats<<<dim3(T_ / 4), blk, 0, stream>>>(ffnout, st2);
    trans_out_ln<<<dim3(16, 12, 16), blk, 0, stream>>>(ffnout, st2, gout, betao, (float*)d_out);
}

// Round 17
// 471.860 us; speedup vs baseline: 1.1167x; 1.1167x over previous
//
#include <hip/hip_runtime.h>
#include <hip/hip_bf16.h>

#define B_ 16
#define C_ 768
#define S_ 1024
#define H_ 12
#define D_ 64
#define I_ 3072
#define T_ (B_ * S_)   // 16384 tokens
#define LOG2E 1.4426950408889634f

typedef unsigned short u16;
typedef unsigned long long u64;
typedef __attribute__((ext_vector_type(8))) short bf16x8;
typedef __attribute__((ext_vector_type(4))) float f32x4;
typedef __attribute__((ext_vector_type(16))) float f32x16;
typedef __attribute__((ext_vector_type(4))) unsigned short us4;

__device__ __forceinline__ u16 bf16b(float f) {
    __hip_bfloat16 h = __float2bfloat16(f);
    return *reinterpret_cast<u16*>(&h);
}
__device__ __forceinline__ float b2f(u16 r) {
    __hip_bfloat16 h = *reinterpret_cast<__hip_bfloat16*>(&r);
    return __bfloat162float(h);
}
// raw v_exp_f32 (2^x), no libm denormal fixup — inputs here are |x| << 126
__device__ __forceinline__ float exp2_raw(float x) {
    return __builtin_amdgcn_exp2f(x);
}

__device__ __forceinline__ void gload16(const void* g, void* l) {
    __builtin_amdgcn_global_load_lds(
        (const __attribute__((address_space(1))) unsigned int*)g,
        (__attribute__((address_space(3))) unsigned int*)l, 16, 0, 0);
}

// ---------------------------------------------------------------------------
// Weight f32 -> bf16: 4 [C,C] mats into contiguous dest
// ---------------------------------------------------------------------------
__global__ __launch_bounds__(256) void cvt_w4(
    const float* __restrict__ w0, const float* __restrict__ w1,
    const float* __restrict__ w2, const float* __restrict__ w3,
    u16* __restrict__ o, int n4) {
    const int sel = blockIdx.y;
    const float* w = sel == 0 ? w0 : sel == 1 ? w1 : sel == 2 ? w2 : w3;
    u16* op = o + (size_t)sel * n4 * 4;
    int i = blockIdx.x * 256 + threadIdx.x;
    if (i < n4) {
        float4 v = ((const float4*)w)[i];
        us4 r = { bf16b(v.x), bf16b(v.y), bf16b(v.z), bf16b(v.w) };
        ((us4*)op)[i] = r;
    }
}
__global__ __launch_bounds__(256) void cvt_w2(
    const float* __restrict__ w0, const float* __restrict__ w1,
    u16* __restrict__ o, int n4) {
    const int sel = blockIdx.y;
    const float* w = sel == 0 ? w0 : w1;
    u16* op = o + (size_t)sel * n4 * 4;
    int i = blockIdx.x * 256 + threadIdx.x;
    if (i < n4) {
        float4 v = ((const float4*)w)[i];
        us4 r = { bf16b(v.x), bf16b(v.y), bf16b(v.z), bf16b(v.w) };
        ((us4*)op)[i] = r;
    }
}

// ---------------------------------------------------------------------------
// x [B,C,S] f32 -> xt16 [B,S,C] bf16
// ---------------------------------------------------------------------------
__global__ __launch_bounds__(256) void trans_in(const float* __restrict__ in,
                                                u16* __restrict__ o16) {
    const int b = blockIdx.z, c0 = blockIdx.y * 64, s0 = blockIdx.x * 64;
    __shared__ float t[64][65];
    const int cl = threadIdx.x & 63, rw = threadIdx.x >> 6;
    #pragma unroll
    for (int p = 0; p < 16; ++p) {
        int cr = rw + p * 4;
        t[cr][cl] = in[((size_t)b * C_ + c0 + cr) * S_ + s0 + cl];
    }
    __syncthreads();
    #pragma unroll
    for (int p = 0; p < 16; ++p) {
        int sr = rw + p * 4;
        o16[((size_t)b * S_ + s0 + sr) * C_ + c0 + cl] = bf16b(t[cl][sr]);
    }
}

// ---------------------------------------------------------------------------
// f32 [B,S,C] -> f32 [B,C,S] with fused LayerNorm apply (stats precomputed)
// ---------------------------------------------------------------------------
__global__ __launch_bounds__(256) void trans_out_ln(
    const float* __restrict__ in, const float2* __restrict__ st,
    const float* __restrict__ g, const float* __restrict__ be,
    float* __restrict__ out) {
    const int b = blockIdx.z, c0 = blockIdx.y * 64, s0 = blockIdx.x * 64;
    __shared__ float t[64][65];
    const int cl = threadIdx.x & 63, rw = threadIdx.x >> 6;
    const float gc = g[c0 + cl], bc = be[c0 + cl];
    #pragma unroll
    for (int p = 0; p < 16; ++p) {
        int sr = rw + p * 4;
        float2 ms = st[(size_t)b * S_ + s0 + sr];
        float v = in[((size_t)b * S_ + s0 + sr) * C_ + c0 + cl];
        t[sr][cl] = (v - ms.x) * ms.y * gc + bc;
    }
    __syncthreads();
    #pragma unroll
    for (int p = 0; p < 16; ++p) {
        int cr = rw + p * 4;
        out[((size_t)b * C_ + c0 + cr) * S_ + s0 + cl] = t[cl][cr];
    }
}

// ---------------------------------------------------------------------------
// bf16 MFMA GEMM, 32x32x16 frags: out[t, o] = sum_k A[t,k] * W[o,k]
// 128(M) x BN tile, BK=64, single-buffer 2-barrier K-loop (measured best;
// explicit dbuf regressed 3x this session: occupancy/conflicts/displacement).
// LDS swizzle S(row) = (row&7)^((row>>3)&1) on 16B chunks (0-conflict).
// 256 threads (4 waves 2x2). XCD-aware bijective block swizzle (grid%8==0).
// MODE 3: out_bf16 = gelu_tanh(acc + bias)   (rcp + raw exp2)
// MODE 5: QKV fused: Q region scaled 0.125*log2e; V region (n0>=1536) is
//         written TRANSPOSED to vt16 [B,C,S] via LDS (res = vt16 ptr).
// MODE 6: out_f32  = acc + bias + bf16(res)
// ---------------------------------------------------------------------------
template <int MODE, int BN>
__global__ __launch_bounds__(256) void gemm_bt(
    const u16* __restrict__ A, int ldA,
    const u16* __restrict__ W, int ldW,
    const float* __restrict__ bias,
    const float* __restrict__ bias2,
    const float* __restrict__ bias3,
    const void* __restrict__ res,
    void* __restrict__ outp, int ldO,
    int K, int nn)
{
    constexpr int NI = BN / 64;     // 32-wide n-frags per wave (128->2, 64->1)
    const int tid = threadIdx.x;
    const int wave = tid >> 6, lane = tid & 63;
    const int wr = wave >> 1, wc = wave & 1;

    // XCD-aware bijective swizzle: XCD x gets a contiguous m-chunk, n fastest
    const int qx = gridDim.x >> 3;
    const int swz = (blockIdx.x & 7) * qx + (blockIdx.x >> 3);
    const int m0 = (swz / nn) * 128, n0 = (swz % nn) * BN;

    __shared__ __align__(16) u16 SB[128 * 64 + BN * 64];   // Al | Bl
    u16* Al = SB;
    u16* Bl = SB + 128 * 64;

    f32x16 acc[2][NI] = {};

    const int srow = tid >> 3;                       // staging row (0..31)
    // inverse-swizzled source chunk: S(srow) = (srow&7)^((srow>>3)&1)
    const int swzc = ((tid & 7) ^ (srow & 7) ^ ((srow >> 3) & 1)) * 8;

    for (int k0 = 0; k0 < K; k0 += 64) {
        __syncthreads();
        #pragma unroll
        for (int p = 0; p < 4; ++p)
            gload16(A + (size_t)(m0 + p * 32 + srow) * ldA + k0 + swzc,
                    Al + p * 2048 + wave * 512);
        #pragma unroll
        for (int p = 0; p < BN / 32; ++p)
            gload16(W + (size_t)(n0 + p * 32 + srow) * ldW + k0 + swzc,
                    Bl + p * 2048 + wave * 512);
        __syncthreads();

        #pragma unroll
        for (int kc = 0; kc < 4; ++kc) {
            bf16x8 aF[2], bF[NI];
            #pragma unroll
            for (int mi = 0; mi < 2; ++mi) {
                int row = wr * 64 + mi * 32 + (lane & 31);
                int ch = (2 * kc + (lane >> 5)) ^ (row & 7) ^ ((row >> 3) & 1);
                aF[mi] = *(const bf16x8*)(Al + row * 64 + ch * 8);
            }
            #pragma unroll
            for (int ni = 0; ni < NI; ++ni) {
                int row = wc * (BN / 2) + ni * 32 + (lane & 31);
                int ch = (2 * kc + (lane >> 5)) ^ (row & 7) ^ ((row >> 3) & 1);
                bF[ni] = *(const bf16x8*)(Bl + row * 64 + ch * 8);
            }
            #pragma unroll
            for (int mi = 0; mi < 2; ++mi)
                #pragma unroll
                for (int ni = 0; ni < NI; ++ni)
                    acc[mi][ni] = __builtin_amdgcn_mfma_f32_32x32x16_bf16(
                        aF[mi], bF[ni], acc[mi][ni], 0, 0, 0);
        }
    }

    // ---- V-block path (MODE 5, n0 >= 1536): bias + LDS transpose -> vt16
    if constexpr (MODE == 5 && BN == 128) {
        if (n0 >= 2 * C_) {
            u16* tile = SB;   // 32KB = 128 cols x 128 rows u16
            __syncthreads();  // all waves done reading staging LDS
            #pragma unroll
            for (int ni = 0; ni < NI; ++ni) {
                const int col = wc * 64 + ni * 32 + (lane & 31);
                const float bo = bias3[n0 - 2 * C_ + col];
                #pragma unroll
                for (int mi = 0; mi < 2; ++mi) {
                    const int rbase = wr * 64 + mi * 32 + 4 * (lane >> 5);
                    #pragma unroll
                    for (int g = 0; g < 4; ++g) {
                        u64 pk = (u64)bf16b(acc[mi][ni][4 * g + 0] + bo)
                               | ((u64)bf16b(acc[mi][ni][4 * g + 1] + bo) << 16)
                               | ((u64)bf16b(acc[mi][ni][4 * g + 2] + bo) << 32)
                               | ((u64)bf16b(acc[mi][ni][4 * g + 3] + bo) << 48);
                        int a = col * 128 + ((rbase + 8 * g) ^ ((col & 31) << 2));
                        *(u64*)(tile + a) = pk;
                    }
                }
            }
            __syncthreads();
            u16* vout = (u16*)res;                 // vt16 [B,C,S]
            const int bb = m0 >> 10, s0 = m0 & 1023;
            #pragma unroll 4
            for (int i = 0; i < 32; ++i) {
                const int c = wave * 32 + i;
                const int a = c * 128 + ((2 * lane) ^ ((c & 31) << 2));
                unsigned w = *(const unsigned*)(tile + a);
                *(unsigned*)(vout + ((size_t)(bb * C_ + (n0 - 2 * C_) + c)) * S_
                             + s0 + 2 * lane) = w;
            }
            return;
        }
    }

    // epilogue; C/D layout: col=lane&31, row=(reg&3)+8*(reg>>2)+4*(lane>>5)
    #pragma unroll
    for (int ni = 0; ni < NI; ++ni) {
        const int o = n0 + wc * (BN / 2) + ni * 32 + (lane & 31);
        float bo, sc = 1.0f;
        if constexpr (MODE == 5) {
            if (o < C_)          { bo = bias[o];            sc = 0.125f * LOG2E; }
            else                 { bo = bias2[o - C_]; }
        } else {
            bo = bias[o];
        }
        #pragma unroll
        for (int mi = 0; mi < 2; ++mi) {
            const int rbase = m0 + wr * 64 + mi * 32 + 4 * (lane >> 5);
            #pragma unroll
            for (int reg = 0; reg < 16; ++reg) {
                const int row = rbase + (reg & 3) + 8 * (reg >> 2);
                const size_t idx = (size_t)row * ldO + o;
                float v = acc[mi][ni][reg];
                if constexpr (MODE == 3) {
                    float u = v + bo;
                    float z2 = (1.5957691216057308f * LOG2E) * (u + 0.044715f * u * u * u);
                    float e = exp2_raw(z2);
                    float r = __builtin_amdgcn_rcpf(e + 1.0f);
                    ((u16*)outp)[idx] = bf16b(u - u * r);
                } else if constexpr (MODE == 5) {
                    ((u16*)outp)[idx] = bf16b((v + bo) * sc);
                } else {  // MODE 6
                    ((float*)outp)[idx] = v + bo + b2f(((const u16*)res)[idx]);
                }
            }
        }
    }
}

// ---------------------------------------------------------------------------
// Flash attention: R6 structure + XCD-grouping swizzle + raw-exp2 softmax +
// T5 s_setprio around MFMA clusters (m191). No-max softmax, deferred
// l-reduction, 40KB LDS rotation: R0=Q then odd-V, R1=even-K, R2=even-V,
// R3=odd-K. global_load_lds prefetch of next K/V tile during compute;
// 1 barrier/iter. Unswapped QK^T; scalar b16 P-stores (0-conflict).
// ---------------------------------------------------------------------------
#define LDQK 2304
__global__ __launch_bounds__(256) void attn(
    const u16* __restrict__ Q, const u16* __restrict__ Kt,
    const u16* __restrict__ VT, const float* __restrict__ mask,
    u16* __restrict__ ctx)
{
    const int tid = threadIdx.x, wave = tid >> 6, lane = tid & 63;

    // XCD-grouping swizzle (bijective): all 16 q-tiles of one (b,h) share
    // l%8 => one XCD under round-robin dispatch.
    const int l = blockIdx.x + 16 * blockIdx.y;   // 0..3071
    const int xc = l & 7, m = l >> 3;             // m: 0..383
    const int bh = xc * 24 + (m >> 4);            // 24 (b,h) pairs per XCD
    const int sq0 = (m & 15) * 64;
    const int b = bh / H_, h = bh - b * H_;

    __shared__ __align__(16) u16 R[4][64 * 64];   // 32KB rotating
    __shared__ __align__(16) u16 Ps[4][16 * 64];  // 8KB

    const int strow0 = tid >> 3;          // staging row, pass 0 (0..31)
    const int strow1 = 32 + (tid >> 3);   // pass 1
    const int stc = tid & 7;              // chunk in row

    auto stageK = [&](int t, u16* dst) {
        const int sk0 = t * 64;
        gload16(Kt + (size_t)(b * S_ + sk0 + strow0) * LDQK + h * 64 + ((stc ^ (strow0 & 7)) * 8),
                dst + wave * 512);
        gload16(Kt + (size_t)(b * S_ + sk0 + strow1) * LDQK + h * 64 + ((stc ^ (strow1 & 7)) * 8),
                dst + 2048 + wave * 512);
    };
    auto stageV = [&](int t, u16* dst) {
        const int sk0 = t * 64;
        gload16(VT + (size_t)(b * C_ + h * 64 + strow0) * S_ + sk0 + ((stc ^ (strow0 & 7)) * 8),
                dst + wave * 512);
        gload16(VT + (size_t)(b * C_ + h * 64 + strow1) * S_ + sk0 + ((stc ^ (strow1 & 7)) * 8),
                dst + 2048 + wave * 512);
    };

    // stage Q into R0, first K/V into R1/R2
    gload16(Q + (size_t)(b * S_ + sq0 + strow0) * LDQK + h * 64 + ((stc ^ (strow0 & 7)) * 8),
            R[0] + wave * 512);
    gload16(Q + (size_t)(b * S_ + sq0 + strow1) * LDQK + h * 64 + ((stc ^ (strow1 & 7)) * 8),
            R[0] + 2048 + wave * 512);
    stageK(0, R[1]);
    stageV(0, R[2]);
    __syncthreads();

    // Q fragments (loop-invariant)
    bf16x8 aQ[2];
    #pragma unroll
    for (int ks = 0; ks < 2; ++ks) {
        int row = wave * 16 + (lane & 15);
        int c16 = ks * 4 + (lane >> 4);
        aQ[ks] = *(const bf16x8*)(R[0] + row * 64 + ((c16 ^ (row & 7)) * 8));
    }
    __syncthreads();   // all aQ reads done before R0 is reused for V1

    f32x4 oacc[4] = {};
    float l_part[4] = {0.f, 0.f, 0.f, 0.f};
    const float* mbase = mask + (size_t)b * S_;

    for (int t = 0; t < 16; ++t) {
        const int sk0 = t * 64;
        const u16* Kc = R[1 + 2 * (t & 1)];       // R1 / R3
        const u16* Vc = R[2 - 2 * (t & 1)];       // R2 / R0
        if (t < 15) {
            stageK(t + 1, R[1 + 2 * ((t + 1) & 1)]);
            stageV(t + 1, R[2 - 2 * ((t + 1) & 1)]);
        }

        // ---- QK^T (Q pre-scaled by 0.125*log2e)
        f32x4 sacc[4] = {};
        __builtin_amdgcn_s_setprio(1);
        #pragma unroll
        for (int ni = 0; ni < 4; ++ni) {
            #pragma unroll
            for (int ks = 0; ks < 2; ++ks) {
                int row = ni * 16 + (lane & 15);
                int c16 = ks * 4 + (lane >> 4);
                bf16x8 bK = *(const bf16x8*)(Kc + row * 64 + ((c16 ^ (row & 7)) * 8));
                sacc[ni] = __builtin_amdgcn_mfma_f32_16x16x32_bf16(aQ[ks], bK, sacc[ni], 0, 0, 0);
            }
        }
        __builtin_amdgcn_s_setprio(0);

        float mk[4];
        #pragma unroll
        for (int ni = 0; ni < 4; ++ni)
            mk[ni] = mbase[sk0 + ni * 16 + (lane & 15)] * LOG2E;

        // ---- no-max softmax numerator: p = 2^(s + mask*log2e), raw v_exp
        #pragma unroll
        for (int r = 0; r < 4; ++r) {
            const int prow = (lane >> 4) * 4 + r;
            #pragma unroll
            for (int ni = 0; ni < 4; ++ni) {
                float p = exp2_raw(sacc[ni][r] + mk[ni]);
                l_part[r] += p;
                int pcol = ni * 16 + (lane & 15);
                int cc = (pcol >> 3) ^ (prow & 7);
                Ps[wave][prow * 64 + cc * 8 + (pcol & 7)] = bf16b(p);
            }
        }

        // ---- PV accumulate (no rescale needed)
        __builtin_amdgcn_s_setprio(1);
        #pragma unroll
        for (int ks = 0; ks < 2; ++ks) {
            int prow = lane & 15;
            int pc16 = ks * 4 + (lane >> 4);
            bf16x8 aP = *(const bf16x8*)(&Ps[wave][prow * 64 + ((pc16 ^ (prow & 7)) * 8)]);
            #pragma unroll
            for (int ni = 0; ni < 4; ++ni) {
                int vrow = ni * 16 + (lane & 15);
                int vc16 = ks * 4 + (lane >> 4);
                bf16x8 bV = *(const bf16x8*)(Vc + vrow * 64 + ((vc16 ^ (vrow & 7)) * 8));
                oacc[ni] = __builtin_amdgcn_mfma_f32_16x16x32_bf16(aP, bV, oacc[ni], 0, 0, 0);
            }
        }
        __builtin_amdgcn_s_setprio(0);
        __syncthreads();   // drains prefetch; guards K/V/Ps region reuse
    }

    // ---- final l reduction (once) + epilogue
    float inv[4];
    #pragma unroll
    for (int r = 0; r < 4; ++r) {
        float lt = l_part[r];
        #pragma unroll
        for (int off = 8; off >= 1; off >>= 1) lt += __shfl_xor(lt, off);
        inv[r] = 1.0f / lt;
    }
    #pragma unroll
    for (int ni = 0; ni < 4; ++ni) {
        #pragma unroll
        for (int r = 0; r < 4; ++r) {
            int rowD = (lane >> 4) * 4 + r;
            int token = b * S_ + sq0 + wave * 16 + rowD;
            int d = ni * 16 + (lane & 15);
            ctx[(size_t)token * C_ + h * 64 + d] = bf16b(oacc[ni][r] * inv[r]);
        }
    }
}

// ---------------------------------------------------------------------------
// Row LayerNorm (token-major). Block = 4 waves = 4 tokens. Full apply -> bf16.
// ---------------------------------------------------------------------------
__global__ __launch_bounds__(256) void ln_rows(
    const float* __restrict__ Y, const float* __restrict__ g,
    const float* __restrict__ be, u16* __restrict__ out16)
{
    const int wave = threadIdx.x >> 6, lane = threadIdx.x & 63;
    const size_t t = blockIdx.x * 4 + wave;
    const float4* y4 = (const float4*)(Y + t * C_);
    float4 v[3];
    float sum = 0.f, ss = 0.f;
    #pragma unroll
    for (int j = 0; j < 3; ++j) {
        v[j] = y4[lane + j * 64];
        sum += v[j].x + v[j].y + v[j].z + v[j].w;
        ss  += v[j].x * v[j].x + v[j].y * v[j].y + v[j].z * v[j].z + v[j].w * v[j].w;
    }
    #pragma unroll
    for (int off = 32; off >= 1; off >>= 1) {
        sum += __shfl_xor(sum, off);
        ss  += __shfl_xor(ss, off);
    }
    const float mu = sum * (1.0f / C_);
    const float var = ss * (1.0f / C_) - mu * mu;
    const float rs = rsqrtf(var + 1e-12f);
    #pragma unroll
    for (int j = 0; j < 3; ++j) {
        int c4 = lane + j * 64;
        float4 gv = ((const float4*)g)[c4];
        float4 bv = ((const float4*)be)[c4];
        us4 pk = { bf16b((v[j].x - mu) * rs * gv.x + bv.x),
                   bf16b((v[j].y - mu) * rs * gv.y + bv.y),
                   bf16b((v[j].z - mu) * rs * gv.z + bv.z),
                   bf16b((v[j].w - mu) * rs * gv.w + bv.w) };
        ((us4*)(out16 + t * C_))[c4] = pk;
    }
}

// ---------------------------------------------------------------------------
// LayerNorm stats only: mu, rstd per token -> float2
// ---------------------------------------------------------------------------
__global__ __launch_bounds__(256) void ln_stats(
    const float* __restrict__ Y, float2* __restrict__ st)
{
    const int wave = threadIdx.x >> 6, lane = threadIdx.x & 63;
    const size_t t = blockIdx.x * 4 + wave;
    const float4* y4 = (const float4*)(Y + t * C_);
    float sum = 0.f, ss = 0.f;
    #pragma unroll
    for (int j = 0; j < 3; ++j) {
        float4 v = y4[lane + j * 64];
        sum += v.x + v.y + v.z + v.w;
        ss  += v.x * v.x + v.y * v.y + v.z * v.z + v.w * v.w;
    }
    #pragma unroll
    for (int off = 32; off >= 1; off >>= 1) {
        sum += __shfl_xor(sum, off);
        ss  += __shfl_xor(ss, off);
    }
    if (lane == 0) {
        const float mu = sum * (1.0f / C_);
        const float var = ss * (1.0f / C_) - mu * mu;
        st[t] = make_float2(mu, rsqrtf(var + 1e-12f));
    }
}

// ---------------------------------------------------------------------------
extern "C" void kernel_launch(void* const* d_in, const int* in_sizes, int n_in,
                              void* d_out, int out_size, void* d_ws, size_t ws_size,
                              hipStream_t stream)
{
    const float* x     = (const float*)d_in[0];
    const float* mask  = (const float*)d_in[1];
    const float* Wq    = (const float*)d_in[2];
    const float* bq    = (const float*)d_in[3];
    const float* Wk    = (const float*)d_in[4];
    const float* bk    = (const float*)d_in[5];
    const float* Wv    = (const float*)d_in[6];
    const float* bv    = (const float*)d_in[7];
    const float* Wpost = (const float*)d_in[8];
    const float* bpost = (const float*)d_in[9];
    const float* gpost = (const float*)d_in[10];
    const float* betap = (const float*)d_in[11];
    const float* Wint  = (const float*)d_in[12];
    const float* bint  = (const float*)d_in[13];
    const float* Wout  = (const float*)d_in[14];
    const float* bout  = (const float*)d_in[15];
    const float* gout  = (const float*)d_in[16];
    const float* betao = (const float*)d_in[17];

    char* ws = (char*)d_ws;
    const size_t OFF0 = 0;                       // ctx16 (25MB) -> ffnout f32 (50MB)
    const size_t OFF1 = 50331648;                // xt16 (25.2MB) -> post16
    const size_t OFF2 = 75497472;                // qkv16 [T,2304] -> postpre -> inter
    const size_t OFF3 = 150994944;               // vt16 (25.2MB) / tail of inter
    const size_t OFFW = 176160768;               // weights (13.5MB)
    const size_t OFFS = 190316544;               // LN2 stats (128KB)

    u16*   ctx16   = (u16*)(ws + OFF0);
    float* ffnout  = (float*)(ws + OFF0);
    u16*   xt16    = (u16*)(ws + OFF1);
    u16*   post16  = (u16*)(ws + OFF1);
    u16*   qkv16   = (u16*)(ws + OFF2);
    float* postpre = (float*)(ws + OFF2);
    u16*   inter   = (u16*)(ws + OFF2);          // [T,3072] bf16 (OFF2+OFF3)
    u16*   vt16    = (u16*)(ws + OFF3);
    float2* st2    = (float2*)(ws + OFFS);

    u16* wq16 = (u16*)(ws + OFFW);               // wq,wk,wv,wp contiguous
    u16* wp16 = wq16 + 3 * (size_t)C_ * C_;
    u16* wi16 = wq16 + 4 * (size_t)C_ * C_;      // wi,wo contiguous
    u16* wo16 = wi16 + (size_t)I_ * C_;

    dim3 blk(256);
    const int n4w = C_ * C_ / 4, n4i = I_ * C_ / 4;
    cvt_w4<<<dim3((n4w + 255) / 256, 4), blk, 0, stream>>>(Wq, Wk, Wv, Wpost, wq16, n4w);
    cvt_w2<<<dim3((n4i + 255) / 256, 2), blk, 0, stream>>>(Wint, Wout, wi16, n4i);

    trans_in<<<dim3(16, 12, 16), blk, 0, stream>>>(x, xt16);

    // fused QKV projection -> Q,K into [T,2304]; V transposed to vt16 [B,C,S]
    gemm_bt<5, 128><<<dim3(128 * 18), blk, 0, stream>>>(xt16, C_, wq16, C_, bq, bk, bv,
                                                        vt16, qkv16, 3 * C_, C_, 18);

    attn<<<dim3(16, B_ * H_), blk, 0, stream>>>(qkv16, qkv16 + C_, vt16, mask, ctx16);

    // post projection + bf16 residual(x) -> f32, then LN1 -> bf16
    gemm_bt<6, 64><<<dim3(128 * 12), blk, 0, stream>>>(ctx16, C_, wp16, C_, bpost, nullptr, nullptr,
                                                       xt16, postpre, C_, C_, 12);
    ln_rows<<<dim3(T_ / 4), blk, 0, stream>>>(postpre, gpost, betap, post16);

    // FFN up (full N=3072) + GELU(tanh,rcp,raw exp2) -> bf16 inter
    gemm_bt<3, 128><<<dim3(128 * 24), blk, 0, stream>>>(post16, C_, wi16, C_, bint, nullptr, nullptr,
                                                        nullptr, inter, I_, C_, 24);
    // FFN down (K=3072) + bf16 residual(post16) -> f32
    gemm_bt<6, 64><<<dim3(128 * 12), blk, 0, stream>>>(inter, I_, wo16, I_, bout, nullptr, nullptr,
                                                       post16, ffnout, C_, I_, 12);

    // LN2: stats pass + apply fused into the output transpose
    ln_stats<<<dim3(T_ / 4), blk, 0, stream>>>(ffnout, st2);
    trans_out_ln<<<dim3(16, 12, 16), blk, 0, stream>>>(ffnout, st2, gout, betao, (float*)d_out);
}